// Round 4
// baseline (412.120 us; speedup 1.0000x reference)
//
#include <hip/hip_runtime.h>

typedef unsigned short ushort_t;
typedef __bf16 bf16x8 __attribute__((ext_vector_type(8)));
typedef float  f32x4  __attribute__((ext_vector_type(4)));

#define MFMA16(a,b,c) __builtin_amdgcn_mfma_f32_16x16x32_bf16((a),(b),(c),0,0,0)

__device__ __forceinline__ ushort_t f2bf(float f) {
    union { float f; unsigned u; } x; x.f = f;
    unsigned r = (x.u + 0x7fffu + ((x.u >> 16) & 1u)) >> 16;
    return (ushort_t)r;
}

// ---------------- fp32 -> bf16 conversion (vectorized) ----------------
__global__ void f2bf_vec(const float* __restrict__ in, ushort_t* __restrict__ out, int n4) {
    int i = blockIdx.x * blockDim.x + threadIdx.x;
    if (i < n4) {
        float4 v = ((const float4*)in)[i];
        ushort4 o;
        o.x = f2bf(v.x); o.y = f2bf(v.y); o.z = f2bf(v.z); o.w = f2bf(v.w);
        ((ushort4*)out)[i] = o;
    }
}

// ---------------- GEMM: C[m,n] = sum_k A[m,k] * W[n,k] (+bias) ----------------
// M=4096, N=1024, K=1024. 128x128 tile, BK=64, 256 threads (4 waves, 2x2).
// MODE 0: write bf16 to Q layout [B,H,S,Dk]; 1: same to K buffer;
// MODE 2: write bf16 to V^T layout [B,H,Dk,S]; 3: write fp32 to d_out.
template<int MODE>
__global__ void gemm_bt(const ushort_t* __restrict__ A,
                        const ushort_t* __restrict__ Bw,
                        const float* __restrict__ bias,
                        void* __restrict__ Cout)
{
    __shared__ __align__(16) char lds[32768];
    char* As = lds;
    char* Bs = lds + 16384;
    const int tid  = threadIdx.x;
    const int lane = tid & 63;
    const int wid  = tid >> 6;
    const int wrow = wid >> 1;
    const int wcol = wid & 1;
    const int m0 = blockIdx.x * 128;
    const int n0 = blockIdx.y * 128;
    const int slot = tid & 7;      // 16B slot within a 128B row
    const int r0   = tid >> 3;     // rows r0 + {0,32,64,96}

    f32x4 acc[4][4] = {};
    float4 pa[4], pb[4];

    #pragma unroll
    for (int i = 0; i < 4; ++i) {
        int row = r0 + i*32;
        pa[i] = *(const float4*)(A  + (size_t)(m0+row)*1024 + slot*8);
        pb[i] = *(const float4*)(Bw + (size_t)(n0+row)*1024 + slot*8);
    }

    for (int kt = 0; kt < 16; ++kt) {
        __syncthreads();
        #pragma unroll
        for (int i = 0; i < 4; ++i) {
            int row = r0 + i*32;
            int off = row*128 + ((slot ^ (row & 7)) << 4);
            *(float4*)(As + off) = pa[i];
            *(float4*)(Bs + off) = pb[i];
        }
        __syncthreads();
        if (kt < 15) {
            int kb = (kt+1)*64;
            #pragma unroll
            for (int i = 0; i < 4; ++i) {
                int row = r0 + i*32;
                pa[i] = *(const float4*)(A  + (size_t)(m0+row)*1024 + kb + slot*8);
                pb[i] = *(const float4*)(Bw + (size_t)(n0+row)*1024 + kb + slot*8);
            }
        }
        #pragma unroll
        for (int ks = 0; ks < 2; ++ks) {
            bf16x8 af[4], bfr[4];
            #pragma unroll
            for (int i = 0; i < 4; ++i) {
                int row = wrow*64 + i*16 + (lane & 15);
                int sl  = ks*4 + (lane >> 4);
                af[i] = *(const bf16x8*)(As + row*128 + ((sl ^ (row & 7)) << 4));
            }
            #pragma unroll
            for (int j = 0; j < 4; ++j) {
                int row = wcol*64 + j*16 + (lane & 15);
                int sl  = ks*4 + (lane >> 4);
                bfr[j] = *(const bf16x8*)(Bs + row*128 + ((sl ^ (row & 7)) << 4));
            }
            #pragma unroll
            for (int i = 0; i < 4; ++i)
                #pragma unroll
                for (int j = 0; j < 4; ++j)
                    acc[i][j] = MFMA16(af[i], bfr[j], acc[i][j]);
        }
    }

    #pragma unroll
    for (int i = 0; i < 4; ++i) {
        #pragma unroll
        for (int j = 0; j < 4; ++j) {
            #pragma unroll
            for (int q = 0; q < 4; ++q) {
                int gm = m0 + wrow*64 + i*16 + (lane >> 4)*4 + q;
                int gn = n0 + wcol*64 + j*16 + (lane & 15);
                float v = acc[i][j][q] + bias[gn];
                if (MODE == 3) {
                    ((float*)Cout)[(size_t)gm*1024 + gn] = v;
                } else {
                    int b = gm >> 11, s = gm & 2047;
                    int h = gn >> 6,  dk = gn & 63;
                    ushort_t bv = f2bf(v);
                    if (MODE == 2)
                        ((ushort_t*)Cout)[((size_t)(b*16+h)*64 + dk)*2048 + s] = bv;
                    else
                        ((ushort_t*)Cout)[((size_t)(b*16+h)*2048 + s)*64 + dk] = bv;
                }
            }
        }
    }
}

// ---------------- sparse flash attention ----------------
// grid: (32 row-blocks, 32 b*h). 256 threads = 4 waves; wave w owns q-rows [16w,16w+16).
__global__ void sparse_attn(const ushort_t* __restrict__ Qg,
                            const ushort_t* __restrict__ Kg,
                            const ushort_t* __restrict__ Vg,   // [B,H,Dk,S]
                            ushort_t* __restrict__ attn)       // [4096,1024]
{
    __shared__ __align__(16) char lds[32768];
    char* Qs = lds;
    char* Ks = lds + 8192;
    char* Vs = lds + 16384;
    char* Ps = lds + 24576;
    const int tid  = threadIdx.x;
    const int lane = tid & 63;
    const int wid  = tid >> 6;
    const int rb   = blockIdx.x;
    const int bh   = blockIdx.y;
    const int slot = tid & 7;
    const int r0   = tid >> 3;   // rows r0, r0+32

    const ushort_t* Qp = Qg + (size_t)bh * 2048 * 64;
    const ushort_t* Kp = Kg + (size_t)bh * 2048 * 64;
    const ushort_t* Vp = Vg + (size_t)bh * 64 * 2048;

    #pragma unroll
    for (int i = 0; i < 2; ++i) {
        int row = r0 + i*32;
        float4 v = *(const float4*)(Qp + (size_t)(rb*64 + row)*64 + slot*8);
        *(float4*)(Qs + row*128 + ((slot ^ (row & 7)) << 4)) = v;
    }
    __syncthreads();

    bf16x8 aq[2];
    #pragma unroll
    for (int ks = 0; ks < 2; ++ks) {
        int row = wid*16 + (lane & 15);
        int sl  = ks*4 + (lane >> 4);
        aq[ks] = *(const bf16x8*)(Qs + row*128 + ((sl ^ (row & 7)) << 4));
    }

    float mrun[4], lrun[4];
    f32x4 oacc[4] = {};
    #pragma unroll
    for (int q = 0; q < 4; ++q) { mrun[q] = -__builtin_inff(); lrun[q] = 0.f; }

    const int i_base = rb*64 + wid*16 + (lane >> 4)*4;

    float4 pk[2], pv[2];
    #pragma unroll
    for (int i = 0; i < 2; ++i) {
        int row = r0 + i*32;
        pk[i] = *(const float4*)(Kp + (size_t)row*64 + slot*8);
        pv[i] = *(const float4*)(Vp + (size_t)row*2048 + slot*8);
    }

    for (int c = 0; c < 32; ++c) {
        __syncthreads();
        #pragma unroll
        for (int i = 0; i < 2; ++i) {
            int row = r0 + i*32;
            int off = row*128 + ((slot ^ (row & 7)) << 4);
            *(float4*)(Ks + off) = pk[i];
            *(float4*)(Vs + off) = pv[i];
        }
        __syncthreads();
        if (c < 31) {
            #pragma unroll
            for (int i = 0; i < 2; ++i) {
                int row = r0 + i*32;
                pk[i] = *(const float4*)(Kp + (size_t)((c+1)*64 + row)*64 + slot*8);
                pv[i] = *(const float4*)(Vp + (size_t)row*2048 + (c+1)*64 + slot*8);
            }
        }
        // QK^T: S[16 x 64] per wave
        f32x4 sacc[4] = {};
        #pragma unroll
        for (int ks = 0; ks < 2; ++ks) {
            bf16x8 bk[4];
            #pragma unroll
            for (int n = 0; n < 4; ++n) {
                int row = n*16 + (lane & 15);
                int sl  = ks*4 + (lane >> 4);
                bk[n] = *(const bf16x8*)(Ks + row*128 + ((sl ^ (row & 7)) << 4));
            }
            #pragma unroll
            for (int n = 0; n < 4; ++n)
                sacc[n] = MFMA16(aq[ks], bk[n], sacc[n]);
        }
        // mask + online softmax
        float sv[4][4];
        #pragma unroll
        for (int n = 0; n < 4; ++n) {
            int j = c*64 + n*16 + (lane & 15);
            #pragma unroll
            for (int q = 0; q < 4; ++q) {
                int ii = i_base + q;
                int d  = j - ii;
                bool valid = (d <= 32 && d >= -32) || ((j & 3) == (ii & 3));
                sv[n][q] = valid ? sacc[n][q] * 0.125f : -1e30f;
            }
        }
        float sc4[4];
        #pragma unroll
        for (int q = 0; q < 4; ++q) {
            float mt = fmaxf(fmaxf(sv[0][q], sv[1][q]), fmaxf(sv[2][q], sv[3][q]));
            mt = fmaxf(mt, __shfl_xor(mt, 1));
            mt = fmaxf(mt, __shfl_xor(mt, 2));
            mt = fmaxf(mt, __shfl_xor(mt, 4));
            mt = fmaxf(mt, __shfl_xor(mt, 8));
            float mn = fmaxf(mrun[q], mt);
            sc4[q] = __expf(mrun[q] - mn);
            mrun[q] = mn;
        }
        float tsum[4] = {0.f, 0.f, 0.f, 0.f};
        #pragma unroll
        for (int n = 0; n < 4; ++n) {
            int colb = (n*16 + (lane & 15)) * 2;
            #pragma unroll
            for (int q = 0; q < 4; ++q) {
                float p = __expf(sv[n][q] - mrun[q]);
                tsum[q] += p;
                int rowp = wid*16 + (lane >> 4)*4 + q;
                *(__bf16*)(Ps + rowp*128 + (colb ^ ((rowp & 7) << 4))) = (__bf16)p;
            }
        }
        #pragma unroll
        for (int q = 0; q < 4; ++q) {
            float t = tsum[q];
            t += __shfl_xor(t, 1);
            t += __shfl_xor(t, 2);
            t += __shfl_xor(t, 4);
            t += __shfl_xor(t, 8);
            lrun[q] = lrun[q]*sc4[q] + t;
        }
        f32x4 scv;
        scv[0] = sc4[0]; scv[1] = sc4[1]; scv[2] = sc4[2]; scv[3] = sc4[3];
        #pragma unroll
        for (int d = 0; d < 4; ++d) oacc[d] *= scv;
        // P·V (P is wave-private in LDS: no extra barrier needed)
        #pragma unroll
        for (int ks = 0; ks < 2; ++ks) {
            int rowp = wid*16 + (lane & 15);
            int sl   = ks*4 + (lane >> 4);
            bf16x8 pf = *(const bf16x8*)(Ps + rowp*128 + ((sl ^ (rowp & 7)) << 4));
            #pragma unroll
            for (int d = 0; d < 4; ++d) {
                int rowv = d*16 + (lane & 15);
                bf16x8 vf = *(const bf16x8*)(Vs + rowv*128 + ((sl ^ (rowv & 7)) << 4));
                oacc[d] = MFMA16(pf, vf, oacc[d]);
            }
        }
    }

    const int b = bh >> 4, h = bh & 15;
    f32x4 invv;
    #pragma unroll
    for (int q = 0; q < 4; ++q) invv[q] = 1.f / lrun[q];
    #pragma unroll
    for (int d = 0; d < 4; ++d) {
        f32x4 o = oacc[d] * invv;
        #pragma unroll
        for (int q = 0; q < 4; ++q) {
            int gr = b*2048 + rb*64 + wid*16 + (lane >> 4)*4 + q;
            int gc = h*64 + d*16 + (lane & 15);
            attn[(size_t)gr*1024 + gc] = f2bf(o[q]);
        }
    }
}

extern "C" void kernel_launch(void* const* d_in, const int* in_sizes, int n_in,
                              void* d_out, int out_size, void* d_ws, size_t ws_size,
                              hipStream_t stream)
{
    const float* x  = (const float*)d_in[0];
    const float* Wq = (const float*)d_in[1];
    const float* bq = (const float*)d_in[2];
    const float* Wk = (const float*)d_in[3];
    const float* bk = (const float*)d_in[4];
    const float* Wv = (const float*)d_in[5];
    const float* bv = (const float*)d_in[6];
    const float* Wo = (const float*)d_in[7];
    const float* bo = (const float*)d_in[8];

    char* ws = (char*)d_ws;
    ushort_t* xbf  = (ushort_t*)(ws);
    ushort_t* wqb  = (ushort_t*)(ws + ((size_t)8  << 20));
    ushort_t* wkb  = (ushort_t*)(ws + ((size_t)10 << 20));
    ushort_t* wvb  = (ushort_t*)(ws + ((size_t)12 << 20));
    ushort_t* wob  = (ushort_t*)(ws + ((size_t)14 << 20));
    ushort_t* Qb   = (ushort_t*)(ws + ((size_t)16 << 20));
    ushort_t* Kb   = (ushort_t*)(ws + ((size_t)24 << 20));
    ushort_t* Vt   = (ushort_t*)(ws + ((size_t)32 << 20));
    ushort_t* attn = (ushort_t*)(ws + ((size_t)40 << 20));

    f2bf_vec<<<4096, 256, 0, stream>>>(x,  xbf, 1048576);
    f2bf_vec<<<1024, 256, 0, stream>>>(Wq, wqb, 262144);
    f2bf_vec<<<1024, 256, 0, stream>>>(Wk, wkb, 262144);
    f2bf_vec<<<1024, 256, 0, stream>>>(Wv, wvb, 262144);
    f2bf_vec<<<1024, 256, 0, stream>>>(Wo, wob, 262144);

    gemm_bt<0><<<dim3(32, 8), 256, 0, stream>>>(xbf, wqb, bq, Qb);
    gemm_bt<1><<<dim3(32, 8), 256, 0, stream>>>(xbf, wkb, bk, Kb);
    gemm_bt<2><<<dim3(32, 8), 256, 0, stream>>>(xbf, wvb, bv, Vt);

    sparse_attn<<<dim3(32, 32), 256, 0, stream>>>(Qb, Kb, Vt, attn);

    gemm_bt<3><<<dim3(32, 8), 256, 0, stream>>>(attn, wob, bo, d_out);
}

// Round 5
// 304.724 us; speedup vs baseline: 1.3524x; 1.3524x over previous
//
#include <hip/hip_runtime.h>

typedef unsigned short ushort_t;
typedef __bf16 bf16x8 __attribute__((ext_vector_type(8)));
typedef float  f32x4  __attribute__((ext_vector_type(4)));

#define MFMA16(a,b,c) __builtin_amdgcn_mfma_f32_16x16x32_bf16((a),(b),(c),0,0,0)

__device__ __forceinline__ ushort_t f2bf(float f) {
    union { float f; unsigned u; } x; x.f = f;
    unsigned r = (x.u + 0x7fffu + ((x.u >> 16) & 1u)) >> 16;
    return (ushort_t)r;
}

// ---------------- fp32 -> bf16 conversion (vectorized) ----------------
__global__ void f2bf_vec(const float* __restrict__ in, ushort_t* __restrict__ out, int n4) {
    int i = blockIdx.x * blockDim.x + threadIdx.x;
    if (i < n4) {
        float4 v = ((const float4*)in)[i];
        ushort4 o;
        o.x = f2bf(v.x); o.y = f2bf(v.y); o.z = f2bf(v.z); o.w = f2bf(v.w);
        ((ushort4*)out)[i] = o;
    }
}

// ---------------- GEMM: C[m,n] = sum_k A[m,k] * W[n,k] (+bias) ----------------
// M=4096, N=1024, K=1024. 128x128 tile, BK=64, 256 threads (4 waves, 2x2).
// MODE 0: bf16 -> Q layout [B,H,S,Dk].
// MODE 1: bf16 -> K normal [B,H,S,Dk] (Cout) AND K strided-compact [B,H,4,512,64] (Cout2).
// MODE 2: bf16 -> V^T normal [B,H,Dk,S] (Cout) AND V^T strided-compact [B,H,4,64,512] (Cout2).
// MODE 3: fp32 -> d_out.
template<int MODE>
__global__ void gemm_bt(const ushort_t* __restrict__ A,
                        const ushort_t* __restrict__ Bw,
                        const float* __restrict__ bias,
                        void* __restrict__ Cout,
                        void* __restrict__ Cout2)
{
    __shared__ __align__(16) char lds[32768];
    char* As = lds;
    char* Bs = lds + 16384;
    const int tid  = threadIdx.x;
    const int lane = tid & 63;
    const int wid  = tid >> 6;
    const int wrow = wid >> 1;
    const int wcol = wid & 1;
    const int m0 = blockIdx.x * 128;
    const int n0 = blockIdx.y * 128;
    const int slot = tid & 7;      // 16B slot within a 128B row
    const int r0   = tid >> 3;     // rows r0 + {0,32,64,96}

    f32x4 acc[4][4] = {};
    float4 pa[4], pb[4];

    #pragma unroll
    for (int i = 0; i < 4; ++i) {
        int row = r0 + i*32;
        pa[i] = *(const float4*)(A  + (size_t)(m0+row)*1024 + slot*8);
        pb[i] = *(const float4*)(Bw + (size_t)(n0+row)*1024 + slot*8);
    }

    for (int kt = 0; kt < 16; ++kt) {
        __syncthreads();
        #pragma unroll
        for (int i = 0; i < 4; ++i) {
            int row = r0 + i*32;
            int off = row*128 + ((slot ^ (row & 7)) << 4);
            *(float4*)(As + off) = pa[i];
            *(float4*)(Bs + off) = pb[i];
        }
        __syncthreads();
        if (kt < 15) {
            int kb = (kt+1)*64;
            #pragma unroll
            for (int i = 0; i < 4; ++i) {
                int row = r0 + i*32;
                pa[i] = *(const float4*)(A  + (size_t)(m0+row)*1024 + kb + slot*8);
                pb[i] = *(const float4*)(Bw + (size_t)(n0+row)*1024 + kb + slot*8);
            }
        }
        #pragma unroll
        for (int ks = 0; ks < 2; ++ks) {
            bf16x8 af[4], bfr[4];
            #pragma unroll
            for (int i = 0; i < 4; ++i) {
                int row = wrow*64 + i*16 + (lane & 15);
                int sl  = ks*4 + (lane >> 4);
                af[i] = *(const bf16x8*)(As + row*128 + ((sl ^ (row & 7)) << 4));
            }
            #pragma unroll
            for (int j = 0; j < 4; ++j) {
                int row = wcol*64 + j*16 + (lane & 15);
                int sl  = ks*4 + (lane >> 4);
                bfr[j] = *(const bf16x8*)(Bs + row*128 + ((sl ^ (row & 7)) << 4));
            }
            #pragma unroll
            for (int i = 0; i < 4; ++i)
                #pragma unroll
                for (int j = 0; j < 4; ++j)
                    acc[i][j] = MFMA16(af[i], bfr[j], acc[i][j]);
        }
    }

    #pragma unroll
    for (int i = 0; i < 4; ++i) {
        #pragma unroll
        for (int j = 0; j < 4; ++j) {
            #pragma unroll
            for (int q = 0; q < 4; ++q) {
                int gm = m0 + wrow*64 + i*16 + (lane >> 4)*4 + q;
                int gn = n0 + wcol*64 + j*16 + (lane & 15);
                float v = acc[i][j][q] + bias[gn];
                if (MODE == 3) {
                    ((float*)Cout)[(size_t)gm*1024 + gn] = v;
                } else {
                    int b = gm >> 11, s = gm & 2047;
                    int h = gn >> 6,  dk = gn & 63;
                    int hh = b*16 + h;
                    ushort_t bv = f2bf(v);
                    if (MODE == 0) {
                        ((ushort_t*)Cout)[((size_t)hh*2048 + s)*64 + dk] = bv;
                    } else if (MODE == 1) {
                        ((ushort_t*)Cout)[((size_t)hh*2048 + s)*64 + dk] = bv;
                        ((ushort_t*)Cout2)[(((size_t)hh*4 + (s & 3))*512 + (s >> 2))*64 + dk] = bv;
                    } else { // MODE == 2
                        ((ushort_t*)Cout)[((size_t)hh*64 + dk)*2048 + s] = bv;
                        ((ushort_t*)Cout2)[(((size_t)hh*4 + (s & 3))*64 + dk)*512 + (s >> 2)] = bv;
                    }
                }
            }
        }
    }
}

// ---------------- online-softmax update (shared by both passes) ----------------
__device__ __forceinline__ void softmax_update(const float sv[4][4], float mrun[4],
                                               float lrun[4], f32x4 oacc[4],
                                               char* Pw, int l15, int lhi)
{
    float sc4[4];
    #pragma unroll
    for (int q = 0; q < 4; ++q) {
        float mt = fmaxf(fmaxf(sv[0][q], sv[1][q]), fmaxf(sv[2][q], sv[3][q]));
        mt = fmaxf(mt, __shfl_xor(mt, 1));
        mt = fmaxf(mt, __shfl_xor(mt, 2));
        mt = fmaxf(mt, __shfl_xor(mt, 4));
        mt = fmaxf(mt, __shfl_xor(mt, 8));
        float mn = fmaxf(mrun[q], mt);
        sc4[q] = __expf(mrun[q] - mn);
        mrun[q] = mn;
    }
    float tsum[4] = {0.f, 0.f, 0.f, 0.f};
    #pragma unroll
    for (int n = 0; n < 4; ++n) {
        int colb = (n*16 + l15) * 2;
        #pragma unroll
        for (int q = 0; q < 4; ++q) {
            float p = __expf(sv[n][q] - mrun[q]);
            tsum[q] += p;
            int rowp = lhi*4 + q;
            *(__bf16*)(Pw + rowp*128 + (colb ^ ((rowp & 7) << 4))) = (__bf16)p;
        }
    }
    #pragma unroll
    for (int q = 0; q < 4; ++q) {
        float t = tsum[q];
        t += __shfl_xor(t, 1);
        t += __shfl_xor(t, 2);
        t += __shfl_xor(t, 4);
        t += __shfl_xor(t, 8);
        lrun[q] = lrun[q]*sc4[q] + t;
    }
    f32x4 scv;
    scv[0] = sc4[0]; scv[1] = sc4[1]; scv[2] = sc4[2]; scv[3] = sc4[3];
    #pragma unroll
    for (int d = 0; d < 4; ++d) oacc[d] *= scv;
}

// ---------------- sparse flash attention v2 (structure-exploiting) ----------------
// grid (32 rb, 32 bh), 256 threads = 4 waves. Wave r owns the 16 rows of the
// 64-row block with (row % 4 == r). Pass 1 (FIRST): 512 strided columns
// j=4t+r, unmasked, 8 chunks of 64 from residue-compacted K/V — no mask at all.
// Pass 2: blocks rb-1..rb+1 with mask (|j-i|<=32 AND j%4 != r).
// No K/V LDS staging (L2-resident, 32 WGs/head reuse); no barriers in main loop.
__global__ void sparse_attn2(const ushort_t* __restrict__ Qg,   // [BH,2048,64]
                             const ushort_t* __restrict__ Kn,   // [BH,2048,64]
                             const ushort_t* __restrict__ Kss,  // [BH,4,512,64]
                             const ushort_t* __restrict__ Vtn,  // [BH,64,2048]
                             const ushort_t* __restrict__ Vts,  // [BH,4,64,512]
                             ushort_t* __restrict__ attn)       // [4096,1024]
{
    __shared__ __align__(16) char Ps[8192];
    const int tid  = threadIdx.x;
    const int lane = tid & 63;
    const int r    = tid >> 6;      // wave id == row residue
    const int l15  = lane & 15;
    const int lhi  = lane >> 4;
    const int rb   = blockIdx.x;
    const int bh   = blockIdx.y;
    char* Pw = Ps + r*2048;

    // Q A-fragments, direct from global: row i(m) = rb*64 + r + 4m, m = l15.
    bf16x8 aq[2];
    {
        const ushort_t* qp = Qg + ((size_t)bh*2048 + rb*64 + r + 4*l15)*64 + lhi*8;
        aq[0] = *(const bf16x8*)(qp);
        aq[1] = *(const bf16x8*)(qp + 32);
    }

    float mrun[4], lrun[4];
    f32x4 oacc[4] = {};
    #pragma unroll
    for (int q = 0; q < 4; ++q) { mrun[q] = -__builtin_inff(); lrun[q] = 0.f; }

    // ---- Pass 1: strided columns (no mask), 8 chunks of 64 t-values ----
    const ushort_t* Kst = Kss + ((size_t)bh*4 + r)*512*64;
    const ushort_t* Vst = Vts + ((size_t)bh*4 + r)*64*512;
    for (int c = 0; c < 8; ++c) {
        const int t0 = c*64;
        f32x4 sacc[4] = {};
        #pragma unroll
        for (int ks = 0; ks < 2; ++ks) {
            bf16x8 bk[4];
            #pragma unroll
            for (int n = 0; n < 4; ++n)
                bk[n] = *(const bf16x8*)(Kst + (size_t)(t0 + n*16 + l15)*64 + ks*32 + lhi*8);
            #pragma unroll
            for (int n = 0; n < 4; ++n)
                sacc[n] = MFMA16(aq[ks], bk[n], sacc[n]);
        }
        float sv[4][4];
        #pragma unroll
        for (int n = 0; n < 4; ++n)
            #pragma unroll
            for (int q = 0; q < 4; ++q)
                sv[n][q] = sacc[n][q] * 0.125f;
        softmax_update(sv, mrun, lrun, oacc, Pw, l15, lhi);
        #pragma unroll
        for (int ks = 0; ks < 2; ++ks) {
            int sl = ks*4 + lhi;
            bf16x8 pf = *(const bf16x8*)(Pw + l15*128 + ((sl ^ (l15 & 7)) << 4));
            #pragma unroll
            for (int d = 0; d < 4; ++d) {
                bf16x8 vf = *(const bf16x8*)(Vst + (size_t)(d*16 + l15)*512 + t0 + ks*32 + lhi*8);
                oacc[d] = MFMA16(pf, vf, oacc[d]);
            }
        }
    }

    // ---- Pass 2: local window minus strided (runs after pass 1: mrun finite) ----
    const int bl0 = (rb > 0)  ? rb-1 : 0;
    const int bl1 = (rb < 31) ? rb+1 : 31;
    const bool notstr = ((l15 & 3) != r);
    for (int bl = bl0; bl <= bl1; ++bl) {
        f32x4 sacc[4] = {};
        #pragma unroll
        for (int ks = 0; ks < 2; ++ks) {
            bf16x8 bk[4];
            #pragma unroll
            for (int n = 0; n < 4; ++n)
                bk[n] = *(const bf16x8*)(Kn + ((size_t)bh*2048 + bl*64 + n*16 + l15)*64 + ks*32 + lhi*8);
            #pragma unroll
            for (int n = 0; n < 4; ++n)
                sacc[n] = MFMA16(aq[ks], bk[n], sacc[n]);
        }
        float sv[4][4];
        #pragma unroll
        for (int n = 0; n < 4; ++n) {
            int j = bl*64 + n*16 + l15;
            #pragma unroll
            for (int q = 0; q < 4; ++q) {
                int i = rb*64 + r + 16*lhi + 4*q;
                int d = j - i;
                bool valid = notstr && (d <= 32) && (d >= -32);
                sv[n][q] = valid ? sacc[n][q] * 0.125f : -1e30f;
            }
        }
        softmax_update(sv, mrun, lrun, oacc, Pw, l15, lhi);
        #pragma unroll
        for (int ks = 0; ks < 2; ++ks) {
            int sl = ks*4 + lhi;
            bf16x8 pf = *(const bf16x8*)(Pw + l15*128 + ((sl ^ (l15 & 7)) << 4));
            #pragma unroll
            for (int d = 0; d < 4; ++d) {
                bf16x8 vf = *(const bf16x8*)(Vtn + ((size_t)bh*64 + d*16 + l15)*2048 + bl*64 + ks*32 + lhi*8);
                oacc[d] = MFMA16(pf, vf, oacc[d]);
            }
        }
    }

    // ---- epilogue ----
    const int b = bh >> 4, h = bh & 15;
    f32x4 invv;
    #pragma unroll
    for (int q = 0; q < 4; ++q) invv[q] = 1.f / lrun[q];
    #pragma unroll
    for (int d = 0; d < 4; ++d) {
        f32x4 o = oacc[d] * invv;
        #pragma unroll
        for (int q = 0; q < 4; ++q) {
            int srow = rb*64 + r + 16*lhi + 4*q;
            int gr = b*2048 + srow;
            int gc = h*64 + d*16 + l15;
            attn[(size_t)gr*1024 + gc] = f2bf(o[q]);
        }
    }
}

extern "C" void kernel_launch(void* const* d_in, const int* in_sizes, int n_in,
                              void* d_out, int out_size, void* d_ws, size_t ws_size,
                              hipStream_t stream)
{
    const float* x  = (const float*)d_in[0];
    const float* Wq = (const float*)d_in[1];
    const float* bq = (const float*)d_in[2];
    const float* Wk = (const float*)d_in[3];
    const float* bk = (const float*)d_in[4];
    const float* Wv = (const float*)d_in[5];
    const float* bv = (const float*)d_in[6];
    const float* Wo = (const float*)d_in[7];
    const float* bo = (const float*)d_in[8];

    char* ws = (char*)d_ws;
    ushort_t* xbf  = (ushort_t*)(ws);                        // 8 MB
    ushort_t* wqb  = (ushort_t*)(ws + ((size_t)8  << 20));   // 2 MB
    ushort_t* wkb  = (ushort_t*)(ws + ((size_t)10 << 20));   // 2 MB
    ushort_t* wvb  = (ushort_t*)(ws + ((size_t)12 << 20));   // 2 MB
    ushort_t* wob  = (ushort_t*)(ws + ((size_t)14 << 20));   // 2 MB
    ushort_t* Qb   = (ushort_t*)(ws + ((size_t)16 << 20));   // 8 MB [BH,S,Dk]
    ushort_t* Kn   = (ushort_t*)(ws + ((size_t)24 << 20));   // 8 MB [BH,S,Dk]
    ushort_t* Kss  = (ushort_t*)(ws + ((size_t)32 << 20));   // 8 MB [BH,4,512,64]
    ushort_t* Vtn  = (ushort_t*)(ws + ((size_t)40 << 20));   // 8 MB [BH,Dk,S]
    ushort_t* Vts  = (ushort_t*)(ws + ((size_t)48 << 20));   // 8 MB [BH,4,64,512]
    ushort_t* attn = (ushort_t*)(ws + ((size_t)56 << 20));   // 8 MB

    f2bf_vec<<<4096, 256, 0, stream>>>(x,  xbf, 1048576);
    f2bf_vec<<<1024, 256, 0, stream>>>(Wq, wqb, 262144);
    f2bf_vec<<<1024, 256, 0, stream>>>(Wk, wkb, 262144);
    f2bf_vec<<<1024, 256, 0, stream>>>(Wv, wvb, 262144);
    f2bf_vec<<<1024, 256, 0, stream>>>(Wo, wob, 262144);

    gemm_bt<0><<<dim3(32, 8), 256, 0, stream>>>(xbf, wqb, bq, Qb, nullptr);
    gemm_bt<1><<<dim3(32, 8), 256, 0, stream>>>(xbf, wkb, bk, Kn, Kss);
    gemm_bt<2><<<dim3(32, 8), 256, 0, stream>>>(xbf, wvb, bv, Vtn, Vts);

    sparse_attn2<<<dim3(32, 32), 256, 0, stream>>>(Qb, Kn, Kss, Vtn, Vts, attn);

    gemm_bt<3><<<dim3(32, 8), 256, 0, stream>>>(attn, wob, bo, d_out, nullptr);
}

// Round 6
// 159.341 us; speedup vs baseline: 2.5864x; 1.9124x over previous
//
#include <hip/hip_runtime.h>

typedef unsigned short ushort_t;
typedef __bf16 bf16x8 __attribute__((ext_vector_type(8)));
typedef float  f32x4  __attribute__((ext_vector_type(4)));

#define MFMA16(a,b,c) __builtin_amdgcn_mfma_f32_16x16x32_bf16((a),(b),(c),0,0,0)

__device__ __forceinline__ ushort_t f2bf(float f) {
    union { float f; unsigned u; } x; x.f = f;
    unsigned r = (x.u + 0x7fffu + ((x.u >> 16) & 1u)) >> 16;
    return (ushort_t)r;
}

__device__ __forceinline__ void gload16(const ushort_t* g, char* l) {
    __builtin_amdgcn_global_load_lds(
        (const __attribute__((address_space(1))) unsigned*)g,
        (__attribute__((address_space(3))) unsigned*)l, 16, 0, 0);
}

// ---------------- fp32 -> bf16 conversion: x ----------------
__global__ void f2bf_vec(const float* __restrict__ in, ushort_t* __restrict__ out, int n4) {
    int i = blockIdx.x * blockDim.x + threadIdx.x;
    if (i < n4) {
        float4 v = ((const float4*)in)[i];
        ushort4 o;
        o.x = f2bf(v.x); o.y = f2bf(v.y); o.z = f2bf(v.z); o.w = f2bf(v.w);
        ((ushort4*)out)[i] = o;
    }
}

// ---------------- all 4 weights cast in one launch ----------------
// wqkv = [Wq;Wk;Wv] as [3072][1024] bf16, wob = Wo [1024][1024] bf16.
__global__ void wcast(const float* __restrict__ Wq, const float* __restrict__ Wk,
                      const float* __restrict__ Wv, const float* __restrict__ Wo,
                      ushort_t* __restrict__ wqkv, ushort_t* __restrict__ wob) {
    int i = blockIdx.x * 256 + threadIdx.x;       // [0, 4*262144)
    int r = i >> 18, j = i & 0x3ffff;
    const float* src = (r == 0) ? Wq : (r == 1) ? Wk : (r == 2) ? Wv : Wo;
    float4 v = ((const float4*)src)[j];
    ushort4 o;
    o.x = f2bf(v.x); o.y = f2bf(v.y); o.z = f2bf(v.z); o.w = f2bf(v.w);
    if (r < 3) ((ushort4*)wqkv)[(size_t)r*262144 + j] = o;
    else       ((ushort4*)wob)[j] = o;
}

// ---------------- GEMM: C[m,n] = sum_k A[m,k]*W[n,k] (+bias) ----------------
// 128x128 tile, BK=64, 256 thr (4 waves 2x2). global_load_lds(16B) staging:
// linear LDS dest + XOR-preswizzled global source + XOR-swizzled ds_read
// (rule 21: source perm == read perm, both involutions).
// MODE 0: NW=3072 QKV fused; routes n-region to Q / K(+Kss) / V^T(+Vts), bf16.
// MODE 1: NW=1024 output proj, fp32 to C0 (+b0 bias).
template<int MODE>
__global__ void gemm_bt(const ushort_t* __restrict__ A,
                        const ushort_t* __restrict__ Bw,
                        const float* __restrict__ b0, const float* __restrict__ b1,
                        const float* __restrict__ b2,
                        void* __restrict__ C0, void* __restrict__ C1,
                        void* __restrict__ C2, void* __restrict__ C3,
                        void* __restrict__ C4)
{
    __shared__ __align__(16) char lds[32768];
    char* As = lds;
    char* Bs = lds + 16384;
    const int tid  = threadIdx.x;
    const int lane = tid & 63;
    const int wid  = tid >> 6;
    const int wrow = wid >> 1;
    const int wcol = wid & 1;
    const int m0 = blockIdx.x * 128;
    const int n0 = blockIdx.y * 128;

    f32x4 acc[4][4] = {};

    // ---- staging: 4 chunks x 256 lanes x 16B covers 128 rows x 128B ----
    // idx = k*256+tid: row = idx>>3, slot s = idx&7; source col-slot = s^(row&7)
    // so LDS-linear (row,s) holds A[row][s^(row&7)] -> read swizzle matches.
    #define STAGE(kb)                                                          \
        _Pragma("unroll")                                                      \
        for (int k = 0; k < 4; ++k) {                                          \
            int idx = k*256 + tid;                                             \
            int row = idx >> 3, s = idx & 7;                                   \
            int sc = s ^ (row & 7);                                            \
            gload16(A  + (size_t)(m0+row)*1024 + (kb) + sc*8, As + idx*16);    \
            gload16(Bw + (size_t)(n0+row)*1024 + (kb) + sc*8, Bs + idx*16);    \
        }

    STAGE(0)
    for (int kt = 0; kt < 16; ++kt) {
        __syncthreads();                  // vmcnt(0) drain: staged tile visible
        #pragma unroll
        for (int ks = 0; ks < 2; ++ks) {
            bf16x8 af[4], bfr[4];
            #pragma unroll
            for (int i = 0; i < 4; ++i) {
                int row = wrow*64 + i*16 + (lane & 15);
                int sl  = ks*4 + (lane >> 4);
                af[i] = *(const bf16x8*)(As + row*128 + ((sl ^ (row & 7)) << 4));
            }
            #pragma unroll
            for (int j = 0; j < 4; ++j) {
                int row = wcol*64 + j*16 + (lane & 15);
                int sl  = ks*4 + (lane >> 4);
                bfr[j] = *(const bf16x8*)(Bs + row*128 + ((sl ^ (row & 7)) << 4));
            }
            #pragma unroll
            for (int i = 0; i < 4; ++i)
                #pragma unroll
                for (int j = 0; j < 4; ++j)
                    acc[i][j] = MFMA16(af[i], bfr[j], acc[i][j]);
        }
        __syncthreads();                  // done reading before overwrite
        if (kt < 15) STAGE((kt+1)*64)
    }
    #undef STAGE

    #pragma unroll
    for (int i = 0; i < 4; ++i) {
        #pragma unroll
        for (int j = 0; j < 4; ++j) {
            #pragma unroll
            for (int q = 0; q < 4; ++q) {
                int gm = m0 + wrow*64 + i*16 + (lane >> 4)*4 + q;
                int gn = n0 + wcol*64 + j*16 + (lane & 15);
                if (MODE == 1) {
                    ((float*)C0)[(size_t)gm*1024 + gn] = acc[i][j][q] + b0[gn];
                } else {
                    int reg = gn >> 10, nn = gn & 1023;
                    float bias = ((reg == 0) ? b0 : (reg == 1) ? b1 : b2)[nn];
                    float v = acc[i][j][q] + bias;
                    int b = gm >> 11, s = gm & 2047;
                    int h = nn >> 6,  dk = nn & 63;
                    int hh = b*16 + h;
                    ushort_t bv = f2bf(v);
                    if (reg == 0) {
                        ((ushort_t*)C0)[((size_t)hh*2048 + s)*64 + dk] = bv;           // Qb
                    } else if (reg == 1) {
                        ((ushort_t*)C1)[((size_t)hh*2048 + s)*64 + dk] = bv;           // Kn
                        ((ushort_t*)C2)[(((size_t)hh*4 + (s & 3))*512 + (s >> 2))*64 + dk] = bv; // Kss
                    } else {
                        ((ushort_t*)C3)[((size_t)hh*64 + dk)*2048 + s] = bv;           // Vtn
                        ((ushort_t*)C4)[(((size_t)hh*4 + (s & 3))*64 + dk)*512 + (s >> 2)] = bv; // Vts
                    }
                }
            }
        }
    }
}

// ---------------- online-softmax update ----------------
__device__ __forceinline__ void softmax_update(const float sv[4][4], float mrun[4],
                                               float lrun[4], f32x4 oacc[4],
                                               char* Pw, int l15, int lhi)
{
    float sc4[4];
    #pragma unroll
    for (int q = 0; q < 4; ++q) {
        float mt = fmaxf(fmaxf(sv[0][q], sv[1][q]), fmaxf(sv[2][q], sv[3][q]));
        mt = fmaxf(mt, __shfl_xor(mt, 1));
        mt = fmaxf(mt, __shfl_xor(mt, 2));
        mt = fmaxf(mt, __shfl_xor(mt, 4));
        mt = fmaxf(mt, __shfl_xor(mt, 8));
        float mn = fmaxf(mrun[q], mt);
        sc4[q] = __expf(mrun[q] - mn);
        mrun[q] = mn;
    }
    float tsum[4] = {0.f, 0.f, 0.f, 0.f};
    #pragma unroll
    for (int n = 0; n < 4; ++n) {
        int colb = (n*16 + l15) * 2;
        #pragma unroll
        for (int q = 0; q < 4; ++q) {
            float p = __expf(sv[n][q] - mrun[q]);
            tsum[q] += p;
            int rowp = lhi*4 + q;
            *(__bf16*)(Pw + rowp*128 + (colb ^ ((rowp & 7) << 4))) = (__bf16)p;
        }
    }
    #pragma unroll
    for (int q = 0; q < 4; ++q) {
        float t = tsum[q];
        t += __shfl_xor(t, 1);
        t += __shfl_xor(t, 2);
        t += __shfl_xor(t, 4);
        t += __shfl_xor(t, 8);
        lrun[q] = lrun[q]*sc4[q] + t;
    }
    f32x4 scv;
    scv[0] = sc4[0]; scv[1] = sc4[1]; scv[2] = sc4[2]; scv[3] = sc4[3];
    #pragma unroll
    for (int d = 0; d < 4; ++d) oacc[d] *= scv;
}

// ---------------- sparse flash attention v3: prefetch + XCD swizzle ----------------
// Linear grid 1024: id' = (id&7)*128 + id>>3 -> each XCD owns 4 heads (L2 reuse).
// Wave r owns rows with row%4==r. Pass 1: 512 strided cols, unmasked, V loaded
// BEFORE QK^T and K[c+1] right after it (latency hides under MFMA+softmax).
// Pass 2: rb-1..rb+1 masked (|j-i|<=32 AND j%4!=r). No barriers in main loop.
__global__ void sparse_attn3(const ushort_t* __restrict__ Qg,
                             const ushort_t* __restrict__ Kn,
                             const ushort_t* __restrict__ Kss,
                             const ushort_t* __restrict__ Vtn,
                             const ushort_t* __restrict__ Vts,
                             ushort_t* __restrict__ attn)
{
    __shared__ __align__(16) char Ps[8192];
    const int tid  = threadIdx.x;
    const int lane = tid & 63;
    const int r    = tid >> 6;
    const int l15  = lane & 15;
    const int lhi  = lane >> 4;
    const int id2  = (blockIdx.x & 7)*128 + (blockIdx.x >> 3);
    const int bh   = id2 >> 5;
    const int rb   = id2 & 31;
    char* Pw = Ps + r*2048;

    bf16x8 aq[2];
    {
        const ushort_t* qp = Qg + ((size_t)bh*2048 + rb*64 + r + 4*l15)*64 + lhi*8;
        aq[0] = *(const bf16x8*)(qp);
        aq[1] = *(const bf16x8*)(qp + 32);
    }

    float mrun[4], lrun[4];
    f32x4 oacc[4] = {};
    #pragma unroll
    for (int q = 0; q < 4; ++q) { mrun[q] = -__builtin_inff(); lrun[q] = 0.f; }

    // ---- Pass 1: strided columns ----
    const ushort_t* Kst = Kss + ((size_t)bh*4 + r)*512*64;
    const ushort_t* Vst = Vts + ((size_t)bh*4 + r)*64*512;

    bf16x8 kc[8];
    #pragma unroll
    for (int ks = 0; ks < 2; ++ks)
        #pragma unroll
        for (int n = 0; n < 4; ++n)
            kc[ks*4+n] = *(const bf16x8*)(Kst + (size_t)(n*16 + l15)*64 + ks*32 + lhi*8);

    for (int c = 0; c < 8; ++c) {
        const int t0 = c*64;
        // V for this chunk, issued before QK^T (hidden under MFMA+softmax)
        bf16x8 vc[8];
        #pragma unroll
        for (int ks = 0; ks < 2; ++ks)
            #pragma unroll
            for (int d = 0; d < 4; ++d)
                vc[ks*4+d] = *(const bf16x8*)(Vst + (size_t)(d*16 + l15)*512 + t0 + ks*32 + lhi*8);
        // QK^T
        f32x4 sacc[4] = {};
        #pragma unroll
        for (int ks = 0; ks < 2; ++ks)
            #pragma unroll
            for (int n = 0; n < 4; ++n)
                sacc[n] = MFMA16(aq[ks], kc[ks*4+n], sacc[n]);
        // prefetch next K chunk (hidden under softmax + PV)
        bf16x8 kn2[8];
        if (c < 7) {
            #pragma unroll
            for (int ks = 0; ks < 2; ++ks)
                #pragma unroll
                for (int n = 0; n < 4; ++n)
                    kn2[ks*4+n] = *(const bf16x8*)(Kst + (size_t)(t0 + 64 + n*16 + l15)*64 + ks*32 + lhi*8);
        }
        float sv[4][4];
        #pragma unroll
        for (int n = 0; n < 4; ++n)
            #pragma unroll
            for (int q = 0; q < 4; ++q)
                sv[n][q] = sacc[n][q] * 0.125f;
        softmax_update(sv, mrun, lrun, oacc, Pw, l15, lhi);
        #pragma unroll
        for (int ks = 0; ks < 2; ++ks) {
            int sl = ks*4 + lhi;
            bf16x8 pf = *(const bf16x8*)(Pw + l15*128 + ((sl ^ (l15 & 7)) << 4));
            #pragma unroll
            for (int d = 0; d < 4; ++d)
                oacc[d] = MFMA16(pf, vc[ks*4+d], oacc[d]);
        }
        if (c < 7) {
            #pragma unroll
            for (int t = 0; t < 8; ++t) kc[t] = kn2[t];
        }
    }

    // ---- Pass 2: local window minus strided ----
    const int bl0 = (rb > 0)  ? rb-1 : 0;
    const int bl1 = (rb < 31) ? rb+1 : 31;
    const bool notstr = ((l15 & 3) != r);
    for (int bl = bl0; bl <= bl1; ++bl) {
        // early V loads
        bf16x8 vc[8];
        #pragma unroll
        for (int ks = 0; ks < 2; ++ks)
            #pragma unroll
            for (int d = 0; d < 4; ++d)
                vc[ks*4+d] = *(const bf16x8*)(Vtn + ((size_t)bh*64 + d*16 + l15)*2048 + bl*64 + ks*32 + lhi*8);
        f32x4 sacc[4] = {};
        #pragma unroll
        for (int ks = 0; ks < 2; ++ks) {
            bf16x8 bk[4];
            #pragma unroll
            for (int n = 0; n < 4; ++n)
                bk[n] = *(const bf16x8*)(Kn + ((size_t)bh*2048 + bl*64 + n*16 + l15)*64 + ks*32 + lhi*8);
            #pragma unroll
            for (int n = 0; n < 4; ++n)
                sacc[n] = MFMA16(aq[ks], bk[n], sacc[n]);
        }
        float sv[4][4];
        #pragma unroll
        for (int n = 0; n < 4; ++n) {
            int j = bl*64 + n*16 + l15;
            #pragma unroll
            for (int q = 0; q < 4; ++q) {
                int i = rb*64 + r + 16*lhi + 4*q;
                int d = j - i;
                bool valid = notstr && (d <= 32) && (d >= -32);
                sv[n][q] = valid ? sacc[n][q] * 0.125f : -1e30f;
            }
        }
        softmax_update(sv, mrun, lrun, oacc, Pw, l15, lhi);
        #pragma unroll
        for (int ks = 0; ks < 2; ++ks) {
            int sl = ks*4 + lhi;
            bf16x8 pf = *(const bf16x8*)(Pw + l15*128 + ((sl ^ (l15 & 7)) << 4));
            #pragma unroll
            for (int d = 0; d < 4; ++d)
                oacc[d] = MFMA16(pf, vc[ks*4+d], oacc[d]);
        }
    }

    // ---- epilogue ----
    const int b = bh >> 4, h = bh & 15;
    f32x4 invv;
    #pragma unroll
    for (int q = 0; q < 4; ++q) invv[q] = 1.f / lrun[q];
    #pragma unroll
    for (int d = 0; d < 4; ++d) {
        f32x4 o = oacc[d] * invv;
        #pragma unroll
        for (int q = 0; q < 4; ++q) {
            int srow = rb*64 + r + 16*lhi + 4*q;
            int gr = b*2048 + srow;
            int gc = h*64 + d*16 + l15;
            attn[(size_t)gr*1024 + gc] = f2bf(o[q]);
        }
    }
}

extern "C" void kernel_launch(void* const* d_in, const int* in_sizes, int n_in,
                              void* d_out, int out_size, void* d_ws, size_t ws_size,
                              hipStream_t stream)
{
    const float* x  = (const float*)d_in[0];
    const float* Wq = (const float*)d_in[1];
    const float* bq = (const float*)d_in[2];
    const float* Wk = (const float*)d_in[3];
    const float* bk = (const float*)d_in[4];
    const float* Wv = (const float*)d_in[5];
    const float* bv = (const float*)d_in[6];
    const float* Wo = (const float*)d_in[7];
    const float* bo = (const float*)d_in[8];

    char* ws = (char*)d_ws;
    ushort_t* xbf  = (ushort_t*)(ws);                        // 8 MB
    ushort_t* wqkv = (ushort_t*)(ws + ((size_t)8  << 20));   // 6 MB [3072][1024]
    ushort_t* wob  = (ushort_t*)(ws + ((size_t)14 << 20));   // 2 MB
    ushort_t* Qb   = (ushort_t*)(ws + ((size_t)16 << 20));   // 8 MB [BH,S,Dk]
    ushort_t* Kn   = (ushort_t*)(ws + ((size_t)24 << 20));   // 8 MB [BH,S,Dk]
    ushort_t* Kss  = (ushort_t*)(ws + ((size_t)32 << 20));   // 8 MB [BH,4,512,64]
    ushort_t* Vtn  = (ushort_t*)(ws + ((size_t)40 << 20));   // 8 MB [BH,Dk,S]
    ushort_t* Vts  = (ushort_t*)(ws + ((size_t)48 << 20));   // 8 MB [BH,4,64,512]
    ushort_t* attn = (ushort_t*)(ws + ((size_t)56 << 20));   // 8 MB

    f2bf_vec<<<4096, 256, 0, stream>>>(x, xbf, 1048576);
    wcast<<<4096, 256, 0, stream>>>(Wq, Wk, Wv, Wo, wqkv, wob);

    gemm_bt<0><<<dim3(32, 24), 256, 0, stream>>>(xbf, wqkv, bq, bk, bv,
                                                 Qb, Kn, Kss, Vtn, Vts);

    sparse_attn3<<<dim3(1024), 256, 0, stream>>>(Qb, Kn, Kss, Vtn, Vts, attn);

    gemm_bt<1><<<dim3(32, 8), 256, 0, stream>>>(attn, wob, bo, nullptr, nullptr,
                                                d_out, nullptr, nullptr, nullptr, nullptr);
}